// Round 1
// 778.463 us; speedup vs baseline: 1.2084x; 1.2084x over previous
//
#include <hip/hip_runtime.h>

#define NSTR 8
#define DM 2048
#define NK 120
#define NKP 128

// ============================================================================
// NEW PATH: mean8 (streaming) -> proj (split-K GEMM, no atomics) -> cayley
// ws layout: xa [npos][2048] f32 at offset 0; zpart [8][npos][128] f32 after.
// ============================================================================

// ---------------- kernel A: xa = mean over 8 streams (pure streaming) --------
// One float4 output per thread; consecutive lanes = consecutive d -> 1KB/instr.
// No LDS, no barriers: 32 waves/CU keep ~100s of KB in flight -> HBM-saturated.
__global__ __launch_bounds__(256)
void mean8(const float4* __restrict__ s4, float4* __restrict__ xa4, int pbase) {
    const size_t idx = (size_t)blockIdx.x * 256 + threadIdx.x; // [0, npos*512)
    const size_t p = idx >> 9;        // local position
    const int d4 = (int)(idx & 511);  // float4 column
    const float4* src = s4 + ((size_t)(pbase) + p) * (NSTR * DM / 4) + d4;
    float4 v = src[0];
#pragma unroll
    for (int n = 1; n < 8; ++n) {
        const float4 u = src[(size_t)n * (DM / 4)];
        v.x += u.x; v.y += u.y; v.z += u.z; v.w += u.w;
    }
    v.x *= 0.125f; v.y *= 0.125f; v.z *= 0.125f; v.w *= 0.125f;
    xa4[idx] = v;
}

// ---------------- kernel B: z-partials = xa * W^T (tiled fp32 GEMM) ----------
// grid = (npos/128) * 8 k-slices; block 256; 2 wg/CU (64 KB LDS).
// Register-staged pipeline (T14): issue next sub-tile's 16 global loads BEFORE
// compute so HBM/L3 latency hides under the 4K-FMA compute phase.
// Each k-slice writes its own partial buffer -> zero atomics, no zero-init.
__global__ __launch_bounds__(256, 2)
void proj(const float* __restrict__ xa, const float* __restrict__ Wm,
          float* __restrict__ zp, int npos) {
    __shared__ float4 sxa[128 * 16];  // 32 KB: xa tile [128 p][64 d], XOR-swizzled
    __shared__ float4 sw[128 * 16];   // 32 KB: W  tile [128 k][64 d], rows>=120 = 0

    const int t = threadIdx.x;
    const int slice = blockIdx.x & 7;   // 0..7  K-slice (256 d each)
    const int ptile = blockIdx.x >> 3;  // position tile
    const int pos0 = ptile * 128;
    const int typ = t >> 4;   // p-octet
    const int txk = t & 15;   // k-octet
    const int c = t & 15;     // staged chunk column
    const int rbase = t >> 4; // staged row base

    float4 ra[8], rw[8];
    float acc[8][8];
#pragma unroll
    for (int i = 0; i < 8; ++i)
#pragma unroll
        for (int j = 0; j < 8; ++j) acc[i][j] = 0.f;

    // ---- prologue: load sub 0 into registers ----
    {
        const int ds0 = slice * 256;
#pragma unroll
        for (int r = 0; r < 8; ++r) {
            const int p = rbase + 16 * r;
            ra[r] = *(const float4*)(xa + (size_t)(pos0 + p) * DM + ds0 + c * 4);
        }
#pragma unroll
        for (int r = 0; r < 8; ++r) {
            const int k = rbase + 16 * r;
            rw[r] = (k < NK) ? *(const float4*)(Wm + (size_t)k * DM + ds0 + c * 4)
                             : make_float4(0.f, 0.f, 0.f, 0.f);
        }
    }

#pragma unroll 1
    for (int sub = 0; sub < 4; ++sub) {
        // ---- write staged registers to (swizzled) LDS ----
#pragma unroll
        for (int r = 0; r < 8; ++r) {
            const int p = rbase + 16 * r;
            sxa[p * 16 + (c ^ (p >> 3))] = ra[r];
        }
#pragma unroll
        for (int r = 0; r < 8; ++r) {
            const int k = rbase + 16 * r;
            sw[k * 16 + (c ^ (k >> 3))] = rw[r];
        }
        __syncthreads();

        // ---- prefetch NEXT sub-tile into registers (overlaps compute) ----
        if (sub < 3) {
            const int ds0 = slice * 256 + (sub + 1) * 64;
#pragma unroll
            for (int r = 0; r < 8; ++r) {
                const int p = rbase + 16 * r;
                ra[r] = *(const float4*)(xa + (size_t)(pos0 + p) * DM + ds0 + c * 4);
            }
#pragma unroll
            for (int r = 0; r < 8; ++r) {
                const int k = rbase + 16 * r;
                rw[r] = (k < NK) ? *(const float4*)(Wm + (size_t)k * DM + ds0 + c * 4)
                                 : make_float4(0.f, 0.f, 0.f, 0.f);
            }
        }

        // ---- GEMM micro-tile: per d-quad, 16 b128 LDS reads feed 256 fmac ----
        for (int dq = 0; dq < 16; ++dq) {
            float4 a[8];
#pragma unroll
            for (int i = 0; i < 8; ++i) a[i] = sxa[(typ * 8 + i) * 16 + (dq ^ typ)];
#pragma unroll
            for (int j = 0; j < 8; ++j) {
                const float4 bv = sw[(txk * 8 + j) * 16 + (dq ^ txk)];
#pragma unroll
                for (int i = 0; i < 8; ++i) {
                    acc[i][j] = fmaf(a[i].x, bv.x, acc[i][j]);
                    acc[i][j] = fmaf(a[i].y, bv.y, acc[i][j]);
                    acc[i][j] = fmaf(a[i].z, bv.z, acc[i][j]);
                    acc[i][j] = fmaf(a[i].w, bv.w, acc[i][j]);
                }
            }
        }
        __syncthreads();
    }

    // ---- store this slice's partial (vectorized, no atomics) ----
    float* base = zp + (size_t)slice * npos * NKP;
#pragma unroll
    for (int i = 0; i < 8; ++i) {
        float* dst = base + (size_t)(pos0 + typ * 8 + i) * NKP + txk * 8;
        *(float4*)dst = make_float4(acc[i][0], acc[i][1], acc[i][2], acc[i][3]);
        *((float4*)dst + 1) = make_float4(acc[i][4], acc[i][5], acc[i][6], acc[i][7]);
    }
}

// ---------------- kernel C: Cayley transform + block-Frobenius ---------------
// One wave per position; 16x16 Gauss-Jordan in registers via shfl.
// NPARTS folds the split-K reduction into the z read (8 partials or 1 buffer).
template <int NPARTS>
__global__ __launch_bounds__(256)
void cayley_k(const float* __restrict__ zb, long long zstride,
              const float* __restrict__ bvec, float* __restrict__ out, int pbase) {
    const int t = threadIdx.x;
    const int wave = t >> 6;
    const int l = t & 63;
    const int pos = blockIdx.x * 4 + wave;   // local position
    const int j = l & 15;
    const int g = l >> 4;

    float m[4], x[4];
#pragma unroll
    for (int r = 0; r < 4; ++r) {
        const int i = 4 * r + g;
        float a;
        if (i != j) {
            int k;
            float sgn;
            if (i < j) { k = (i * (31 - i)) / 2 + (j - i - 1); sgn = 1.f; }
            else       { k = (j * (31 - j)) / 2 + (i - j - 1); sgn = -1.f; }
            const size_t off = (size_t)pos * NKP + k;
            float zv = zb[off];
#pragma unroll
            for (int s = 1; s < NPARTS; ++s) zv += zb[off + (size_t)s * zstride];
            a = sgn * (zv + bvec[k]);
        } else {
            a = 0.f;
        }
        const float d = (i == j) ? 1.f : 0.f;
        m[r] = d + a;   // M = I + A
        x[r] = d - a;   // X = I - A  (becomes Q after solve)
    }

#pragma unroll
    for (int k = 0; k < 16; ++k) {
        const int rr = k >> 2;
        const int src_row = (k & 3) << 4;
        const float mk  = __shfl(m[rr], src_row | j, 64);
        const float xk  = __shfl(x[rr], src_row | j, 64);
        const float mkk = __shfl(m[rr], src_row | k, 64);
        const float rk = 1.0f / mkk;
#pragma unroll
        for (int r = 0; r < 4; ++r) {
            const float mik = __shfl(m[r], (g << 4) | k, 64);
            const float f = (4 * r + g == k) ? 0.f : mik * rk;
            m[r] = fmaf(-f, mk, m[r]);
            x[r] = fmaf(-f, xk, x[r]);
        }
    }

    float h[4];
#pragma unroll
    for (int r = 0; r < 4; ++r) {
        const int i = 4 * r + g;
        const float mdiag = __shfl(m[r], (g << 4) | i, 64);
        const float q = x[r] / mdiag;
        float s = q * q;
        s += __shfl_xor(s, 1, 64);
        s += __shfl_xor(s, 16, 64);
        h[r] = s * 0.5f;
    }
    if (((j & 1) == 0) && ((g & 1) == 0)) {
        const int col = j >> 1;
#pragma unroll
        for (int r = 0; r < 4; ++r) {
            const int row = 2 * r + (g >> 1);
            out[(size_t)(pbase + pos) * 64 + row * 8 + col] = h[r];
        }
    }
}

// ============================================================================
// FALLBACK PATH (workspace too small): previous verified kernels, unchanged.
// ============================================================================
#define TM 128
#define DSLICE 256
#define SD 64

__global__ void zero_ws(float4* z4) {
    z4[(size_t)blockIdx.x * 256 + threadIdx.x] = make_float4(0.f, 0.f, 0.f, 0.f);
}

__global__ __launch_bounds__(256, 2)
void mean_proj_fused(const float* __restrict__ streams, const float* __restrict__ W,
                     float* __restrict__ z) {
    __shared__ float4 sxa[TM * 16];
    __shared__ float4 sw[NKP * 16];

    const int t = threadIdx.x;
    const int bid = blockIdx.x;
    const int slice = bid >> 6;
    const int ptile = bid & 63;
    const int pos0 = ptile * TM;
    const int typ = t >> 4;
    const int txk = t & 15;

    float acc[8][8];
#pragma unroll
    for (int i = 0; i < 8; ++i)
#pragma unroll
        for (int j = 0; j < 8; ++j) acc[i][j] = 0.f;

    for (int sub = 0; sub < 4; ++sub) {
        const int ds0 = slice * DSLICE + sub * SD;
#pragma unroll
        for (int r = 0; r < 8; ++r) {
            const int item = t + 256 * r;
            const int p = item >> 4;
            const int dq = item & 15;
            const float4* src = (const float4*)(streams
                + (size_t)(pos0 + p) * NSTR * DM + ds0 + dq * 4);
            float4 v = src[0];
#pragma unroll
            for (int n = 1; n < 8; ++n) {
                const float4 u = src[n * (DM / 4)];
                v.x += u.x; v.y += u.y; v.z += u.z; v.w += u.w;
            }
            v.x *= 0.125f; v.y *= 0.125f; v.z *= 0.125f; v.w *= 0.125f;
            sxa[p * 16 + (dq ^ (p >> 3))] = v;
        }
#pragma unroll
        for (int r = 0; r < 8; ++r) {
            const int item = t + 256 * r;
            const int k = item >> 4;
            const int dq = item & 15;
            float4 v = make_float4(0.f, 0.f, 0.f, 0.f);
            if (k < NK) v = *(const float4*)(W + (size_t)k * DM + ds0 + dq * 4);
            sw[k * 16 + (dq ^ (k >> 3))] = v;
        }
        __syncthreads();

        for (int dq = 0; dq < 16; ++dq) {
            float4 a[8];
#pragma unroll
            for (int i = 0; i < 8; ++i) a[i] = sxa[(typ * 8 + i) * 16 + (dq ^ typ)];
#pragma unroll
            for (int j = 0; j < 8; ++j) {
                const float4 bv = sw[(txk * 8 + j) * 16 + (dq ^ txk)];
#pragma unroll
                for (int i = 0; i < 8; ++i) {
                    acc[i][j] = fmaf(a[i].x, bv.x, acc[i][j]);
                    acc[i][j] = fmaf(a[i].y, bv.y, acc[i][j]);
                    acc[i][j] = fmaf(a[i].z, bv.z, acc[i][j]);
                    acc[i][j] = fmaf(a[i].w, bv.w, acc[i][j]);
                }
            }
        }
        __syncthreads();
    }

#pragma unroll
    for (int i = 0; i < 8; ++i) {
        const size_t p = (size_t)pos0 + typ * 8 + i;
#pragma unroll
        for (int j = 0; j < 8; ++j) {
            const int k = txk * 8 + j;
            if (k < NK) atomicAdd(&z[p * NKP + k], acc[i][j]);
        }
    }
}

// ---------------- launcher ---------------------------------------------------
extern "C" void kernel_launch(void* const* d_in, const int* in_sizes, int n_in,
                              void* d_out, int out_size, void* d_ws, size_t ws_size,
                              hipStream_t stream) {
    const float* streams = (const float*)d_in[0];  // [2,4096,8,2048] fp32
    const float* W       = (const float*)d_in[1];  // [120,2048] fp32
    const float* bvec    = (const float*)d_in[2];  // [120] fp32
    float* out = (float*)d_out;                    // [2,4096,8,8] fp32

    const size_t TOTPOS = 8192;
    const size_t XA_FULL = TOTPOS * DM * sizeof(float);          // 64 MiB
    const size_t ZP_FULL = 8 * TOTPOS * NKP * sizeof(float);     // 32 MiB

    int nb = 0;
    size_t npos = 0;
    if (ws_size >= XA_FULL + ZP_FULL)               { nb = 1; npos = 8192; }
    else if (ws_size >= (XA_FULL + ZP_FULL) / 2)    { nb = 2; npos = 4096; }

    if (nb > 0) {
        float* xa = (float*)d_ws;
        float* zp = (float*)((char*)d_ws + npos * DM * sizeof(float));
        const long long zstride = (long long)npos * NKP;
        for (int b = 0; b < nb; ++b) {
            const int pbase = (int)(b * npos);
            mean8<<<(int)(npos * 2), 256, 0, stream>>>(
                (const float4*)streams, (float4*)xa, pbase);
            proj<<<(int)((npos / 128) * 8), 256, 0, stream>>>(xa, W, zp, (int)npos);
            cayley_k<8><<<(int)(npos / 4), 256, 0, stream>>>(zp, zstride, bvec, out, pbase);
        }
    } else {
        // fallback: previous verified path (needs only 4 MiB ws)
        float* z = (float*)d_ws;
        zero_ws<<<1024, 256, 0, stream>>>((float4*)d_ws);
        mean_proj_fused<<<512, 256, 0, stream>>>(streams, W, z);
        cayley_k<1><<<2048, 256, 0, stream>>>(z, 0, bvec, out, 0);
    }
}